// Round 1
// 962.761 us; speedup vs baseline: 1.4385x; 1.4385x over previous
//
#include <hip/hip_runtime.h>
#include <cstdint>

typedef __bf16 bf16_t;
typedef __bf16 bf16x8 __attribute__((ext_vector_type(8)));
typedef float f32x4 __attribute__((ext_vector_type(4)));

#define AS1 __attribute__((address_space(1)))
#define AS3 __attribute__((address_space(3)))

__device__ __forceinline__ void gload_lds16(const bf16_t* g, bf16_t* l) {
    __builtin_amdgcn_global_load_lds((const AS1 void*)g, (AS3 void*)l, 16, 0, 0);
}
__device__ __forceinline__ f32x4 mfma_bf16(bf16x8 a, bf16x8 b, f32x4 c) {
    return __builtin_amdgcn_mfma_f32_16x16x32_bf16(a, b, c, 0, 0, 0);
}

// C[row,col] = sum_k A[row,k]*B[col,k] (+bias). 128x128 tile, BK=32, 256 thr.
// SPLIT: A,B given as (hi,lo) bf16 pairs; computes Ah*Bh + Ah*Bl + Al*Bh.
// BIAS: 0=none, 1=+bias[col], 2=+bias[row] (fp32 bias).
// OUTMODE: 0 = fp32 -> C0; 1 = bf16 -> C0; 2 = split: hi bf16 -> C0, lo bf16 -> C1.
//
// LDS layout: [128 rows][4 x 16B k-chunks], XOR-swizzled: physical slot p of row r
// holds logical k-chunk (p ^ ((r>>1)&3)).  Swizzle is applied on BOTH sides
// (pre-swizzled global source for global_load_lds + swizzled ds_read addr), so the
// 16-lane fragment reads spread uniformly 2-way across all 32 banks (conflict-free)
// instead of the 8-way conflict of the linear layout (row stride 64B).
template <bool SPLIT, int BIAS, int OUTMODE>
__global__ __launch_bounds__(256) void gemm_bt(
    const bf16_t* __restrict__ Ah, const bf16_t* __restrict__ Al, long long strideA, int lda,
    const bf16_t* __restrict__ Bh, const bf16_t* __restrict__ Bl, long long strideB, int ldb,
    void* __restrict__ C0, void* __restrict__ C1, long long strideC, int ldc,
    const float* __restrict__ bias, int K)
{
    __shared__ bf16_t Ash[128 * 32];
    __shared__ bf16_t Bsh[128 * 32];
    __shared__ bf16_t Asl[SPLIT ? 128 * 32 : 8];
    __shared__ bf16_t Bsl[SPLIT ? 128 * 32 : 8];

    const int bz = blockIdx.z;
    const int rowBase = blockIdx.y * 128;
    const int colBase = blockIdx.x * 128;
    const bf16_t* AhB = Ah + (long long)bz * strideA;
    const bf16_t* BhB = Bh + (long long)bz * strideB;
    const bf16_t* AlB = SPLIT ? Al + (long long)bz * strideA : nullptr;
    const bf16_t* BlB = SPLIT ? Bl + (long long)bz * strideB : nullptr;

    const int t = threadIdx.x;
    const int lane = t & 63;
    const int w = t >> 6;
    const int wr = (w >> 1) * 64;
    const int wc = (w & 1) * 64;

    f32x4 acc[4][4] = {};

    const int r0 = t >> 2;                                   // staging row (tile-local, 0..63)
    // pre-swizzled k-chunk for the staging source: slot (t&3) of row r0 receives
    // logical chunk (t&3) ^ ((r0>>1)&3).  Note ((r0+64)>>1)&3 == (r0>>1)&3, so the
    // same offset serves both 64-row halves.
    const int kc0 = (((t & 3) ^ ((r0 >> 1) & 3)) * 8);

    for (int k0 = 0; k0 < K; k0 += 32) {
        const long long aoff0 = (long long)(rowBase + r0) * lda + k0 + kc0;
        const long long aoff1 = (long long)(rowBase + r0 + 64) * lda + k0 + kc0;
        const long long boff0 = (long long)(colBase + r0) * ldb + k0 + kc0;
        const long long boff1 = (long long)(colBase + r0 + 64) * ldb + k0 + kc0;
        gload_lds16(AhB + aoff0, &Ash[t * 8]);
        gload_lds16(AhB + aoff1, &Ash[(t + 256) * 8]);
        gload_lds16(BhB + boff0, &Bsh[t * 8]);
        gload_lds16(BhB + boff1, &Bsh[(t + 256) * 8]);
        if (SPLIT) {
            gload_lds16(AlB + aoff0, &Asl[t * 8]);
            gload_lds16(AlB + aoff1, &Asl[(t + 256) * 8]);
            gload_lds16(BlB + boff0, &Bsl[t * 8]);
            gload_lds16(BlB + boff1, &Bsl[(t + 256) * 8]);
        }
        __syncthreads();

        const int fr = lane & 15;
        // swizzled read: logical chunk (lane>>4) of row R lives at physical slot
        // (lane>>4) ^ ((R>>1)&3); (R>>1)&3 == (lane>>1)&3 since wr, mi*16 are
        // multiples of 8 in the row index.
        const int kqs = (((lane >> 4) ^ ((lane >> 1) & 3)) * 8);
        bf16x8 ah[4], bh[4], al[4], bl[4];
#pragma unroll
        for (int mi = 0; mi < 4; mi++) {
            ah[mi] = *(const bf16x8*)&Ash[(wr + mi * 16 + fr) * 32 + kqs];
            if (SPLIT) al[mi] = *(const bf16x8*)&Asl[(wr + mi * 16 + fr) * 32 + kqs];
        }
#pragma unroll
        for (int ni = 0; ni < 4; ni++) {
            bh[ni] = *(const bf16x8*)&Bsh[(wc + ni * 16 + fr) * 32 + kqs];
            if (SPLIT) bl[ni] = *(const bf16x8*)&Bsl[(wc + ni * 16 + fr) * 32 + kqs];
        }

#pragma unroll
        for (int mi = 0; mi < 4; mi++)
#pragma unroll
            for (int ni = 0; ni < 4; ni++) {
                if (SPLIT) {
                    acc[mi][ni] = mfma_bf16(al[mi], bh[ni], acc[mi][ni]);
                    acc[mi][ni] = mfma_bf16(ah[mi], bl[ni], acc[mi][ni]);
                }
                acc[mi][ni] = mfma_bf16(ah[mi], bh[ni], acc[mi][ni]);
            }
        __syncthreads();
    }

    // epilogue: C/D layout col = lane&15, row = (lane>>4)*4 + reg
    const int fc = lane & 15;
    const int fr4 = (lane >> 4) * 4;
#pragma unroll
    for (int mi = 0; mi < 4; mi++)
#pragma unroll
        for (int ni = 0; ni < 4; ni++)
#pragma unroll
            for (int rg = 0; rg < 4; rg++) {
                const int row = rowBase + wr + mi * 16 + fr4 + rg;
                const int col = colBase + wc + ni * 16 + fc;
                float v = acc[mi][ni][rg];
                if (BIAS == 1) v += bias[col];
                else if (BIAS == 2) v += bias[row];
                const long long off = (long long)bz * strideC + (long long)row * ldc + col;
                if (OUTMODE == 0) {
                    ((float*)C0)[off] = v;
                } else if (OUTMODE == 1) {
                    ((bf16_t*)C0)[off] = (bf16_t)v;
                } else {
                    const bf16_t h = (bf16_t)v;
                    ((bf16_t*)C0)[off] = h;
                    ((bf16_t*)C1)[off] = (bf16_t)(v - (float)h);
                }
            }
}

// fp32 -> (hi, lo) bf16 split; n multiple of 1024; grid = n/1024 blocks of 256.
__global__ __launch_bounds__(256) void split_f32(const float* __restrict__ x,
                                                 bf16_t* __restrict__ h,
                                                 bf16_t* __restrict__ l)
{
    const long long i = ((long long)blockIdx.x * 256 + threadIdx.x) * 4;
    const float4 v = *(const float4*)&x[i];
    bf16_t hh[4], ll[4];
    const float vv[4] = {v.x, v.y, v.z, v.w};
#pragma unroll
    for (int j = 0; j < 4; j++) {
        hh[j] = (bf16_t)vv[j];
        ll[j] = (bf16_t)(vv[j] - (float)hh[j]);
    }
    *(short4*)&h[i] = *(short4*)hh;
    *(short4*)&l[i] = *(short4*)ll;
}

// fp32 -> bf16 cast; n multiple of 1024; grid = n/1024.
__global__ __launch_bounds__(256) void cast_f32(const float* __restrict__ x,
                                                bf16_t* __restrict__ y)
{
    const long long i = ((long long)blockIdx.x * 256 + threadIdx.x) * 4;
    const float4 v = *(const float4*)&x[i];
    bf16_t hh[4] = {(bf16_t)v.x, (bf16_t)v.y, (bf16_t)v.z, (bf16_t)v.w};
    *(short4*)&y[i] = *(short4*)hh;
}

// Row softmax with mask; S fp32 [rows][2048] -> P bf16 [rows][2048].
// mask row = n0 + (r & 2047)  (r&2047 = row-within-batch for the z-batched path).
__global__ __launch_bounds__(256) void softmax_rows(const float* __restrict__ S,
                                                    bf16_t* __restrict__ P,
                                                    const int* __restrict__ mask,
                                                    int n0)
{
    __shared__ float red[4];
    const long long r = blockIdx.x;
    const float* row = S + r * 2048;
    const int* mrow = mask + (long long)(n0 + (int)(r & 2047)) * 2048;
    const int t = threadIdx.x;

    float v[8];
#pragma unroll
    for (int i = 0; i < 8; i++) {
        const int j = i * 256 + t;
        v[i] = (mrow[j] != 0) ? row[j] : -1000000000.0f;
    }
    float m = v[0];
#pragma unroll
    for (int i = 1; i < 8; i++) m = fmaxf(m, v[i]);
#pragma unroll
    for (int off = 32; off; off >>= 1) m = fmaxf(m, __shfl_xor(m, off));
    if ((t & 63) == 0) red[t >> 6] = m;
    __syncthreads();
    const float rowmax = fmaxf(fmaxf(red[0], red[1]), fmaxf(red[2], red[3]));
    __syncthreads();

    float sum = 0.0f;
    float e[8];
#pragma unroll
    for (int i = 0; i < 8; i++) { e[i] = __expf(v[i] - rowmax); sum += e[i]; }
#pragma unroll
    for (int off = 32; off; off >>= 1) sum += __shfl_xor(sum, off);
    if ((t & 63) == 0) red[t >> 6] = sum;
    __syncthreads();
    const float inv = 1.0f / (red[0] + red[1] + red[2] + red[3]);

    bf16_t* prow = P + r * 2048;
#pragma unroll
    for (int i = 0; i < 8; i++) prow[i * 256 + t] = (bf16_t)(e[i] * inv);
}

extern "C" void kernel_launch(void* const* d_in, const int* in_sizes, int n_in,
                              void* d_out, int out_size, void* d_ws, size_t ws_size,
                              hipStream_t stream) {
    constexpr int Bb = 8, N = 2048, M = 2048, D = 1024;
    constexpr long long MB = 1LL << 20;

    const float* querys = (const float*)d_in[0];
    const float* keys   = (const float*)d_in[1];
    const float* values = (const float*)d_in[2];
    const int*   mask   = (const int*)d_in[3];
    const float* Wq = (const float*)d_in[4];
    const float* bq = (const float*)d_in[5];
    const float* Wk = (const float*)d_in[6];
    const float* bk = (const float*)d_in[7];
    const float* Wv = (const float*)d_in[8];
    const float* bv = (const float*)d_in[9];
    float* out = (float*)d_out;

    // ---- adaptive plan ----
    // Batched path (z-batched attention GEMMs, full-grid occupancy):
    //   need(CB) = 10 MiB (weights) + CB * 52 MiB
    //   (X hi/lo: 8, Q hi/lo: 8, K hi/lo: 8, VT: 4, S fp32: 16, P bf16: 8 per batch)
    // Fallback (tiny ws): CB=1 with n-chunked attention (legacy behavior).
    const long long w = (long long)ws_size;
    auto needB = [&](long long cb) { return 10 * MB + cb * 52 * MB; };
    int CB = 0;
    if      (w >= needB(8)) CB = 8;
    else if (w >= needB(4)) CB = 4;
    else if (w >= needB(2)) CB = 2;
    else if (w >= needB(1)) CB = 1;
    const bool batched = (CB != 0);
    int NCH = N;
    if (!batched) {
        CB = 1;
        NCH = (w >= 38 * MB + 512 * 2048 * 6) ? 512 : 128;
    }

    char* ws = (char*)d_ws;
    long long o = 0;
    auto carve = [&](long long bytes) { char* p = ws + o; o += bytes; return p; };
    bf16_t* WqH = (bf16_t*)carve(2 * MB);
    bf16_t* WqL = (bf16_t*)carve(2 * MB);
    bf16_t* WkH = (bf16_t*)carve(2 * MB);
    bf16_t* WkL = (bf16_t*)carve(2 * MB);
    bf16_t* WvB = (bf16_t*)carve(2 * MB);
    bf16_t* XH  = (bf16_t*)carve((long long)CB * 4 * MB);  // also reused as V staging
    bf16_t* XL  = (bf16_t*)carve((long long)CB * 4 * MB);
    bf16_t* QH  = (bf16_t*)carve((long long)CB * 4 * MB);
    bf16_t* QL  = (bf16_t*)carve((long long)CB * 4 * MB);
    bf16_t* KH  = (bf16_t*)carve((long long)CB * 4 * MB);
    bf16_t* KL  = (bf16_t*)carve((long long)CB * 4 * MB);
    bf16_t* VT  = (bf16_t*)carve((long long)CB * 4 * MB);  // [CB][D][M]
    float*  S   = (float*)carve(batched ? (long long)CB * N * M * 4 : (long long)NCH * 2048 * 4);
    bf16_t* P   = (bf16_t*)carve(batched ? (long long)CB * N * M * 2 : (long long)NCH * 2048 * 2);

    dim3 blk(256);
    const long long grpElems = (long long)CB * N * D;  // per-group x elements

    // weight conversions (once)
    split_f32<<<dim3((D * D) / 1024), blk, 0, stream>>>(Wq, WqH, WqL);
    split_f32<<<dim3((D * D) / 1024), blk, 0, stream>>>(Wk, WkH, WkL);
    cast_f32<<<dim3((D * D) / 1024), blk, 0, stream>>>(Wv, WvB);

    for (int b0 = 0; b0 < Bb; b0 += CB) {
        const long long xoff = (long long)b0 * N * D;
        // q = xq @ Wq^T + bq  -> split  (rows = CB*N)
        split_f32<<<dim3(grpElems / 1024), blk, 0, stream>>>(querys + xoff, XH, XL);
        gemm_bt<true, 1, 2><<<dim3(D / 128, CB * N / 128, 1), blk, 0, stream>>>(
            XH, XL, 0, D, WqH, WqL, 0, D, QH, QL, 0, D, bq, D);
        // k = xk @ Wk^T + bk  -> split
        split_f32<<<dim3(grpElems / 1024), blk, 0, stream>>>(keys + xoff, XH, XL);
        gemm_bt<true, 1, 2><<<dim3(D / 128, CB * M / 128, 1), blk, 0, stream>>>(
            XH, XL, 0, D, WkH, WkL, 0, D, KH, KL, 0, D, bk, D);
        // vT[z][d][m] = sum_e Wv[d][e]*xv[z][m][e] + bv[d]   (plain bf16; XH = V staging)
        cast_f32<<<dim3(grpElems / 1024), blk, 0, stream>>>(values + xoff, XH);
        gemm_bt<false, 2, 1><<<dim3(M / 128, D / 128, CB), blk, 0, stream>>>(
            WvB, nullptr, 0, D, XH, nullptr, (long long)M * D, D,
            VT, nullptr, (long long)D * M, M, bv, D);

        if (batched) {
            // S[z][n][m] = q[z][n] . k[z][m]   (fp32, split GEMM, all z at once)
            gemm_bt<true, 0, 0><<<dim3(M / 128, N / 128, CB), blk, 0, stream>>>(
                QH, QL, (long long)N * D, D,
                KH, KL, (long long)M * D, D,
                S, nullptr, (long long)N * M, M, nullptr, D);
            // P = softmax(mask ? S : NEG)  (bf16), all z at once
            softmax_rows<<<dim3(CB * N), blk, 0, stream>>>(S, P, mask, 0);
            // out[b0+z][n][d] = sum_m P[z][n][m] * vT[z][d][m]   (fp32 out)
            gemm_bt<false, 0, 0><<<dim3(D / 128, N / 128, CB), blk, 0, stream>>>(
                P, nullptr, (long long)N * M, M,
                VT, nullptr, (long long)D * M, M,
                out + xoff, nullptr, (long long)N * D, D, nullptr, M);
        } else {
            for (int z = 0; z < CB; z++) {
                for (int n0 = 0; n0 < N; n0 += NCH) {
                    gemm_bt<true, 0, 0><<<dim3(M / 128, NCH / 128, 1), blk, 0, stream>>>(
                        QH + ((long long)z * N + n0) * D, QL + ((long long)z * N + n0) * D, 0, D,
                        KH + (long long)z * M * D, KL + (long long)z * M * D, 0, D,
                        S, nullptr, 0, M, nullptr, D);
                    softmax_rows<<<dim3(NCH), blk, 0, stream>>>(S, P, mask, n0);
                    gemm_bt<false, 0, 0><<<dim3(D / 128, NCH / 128, 1), blk, 0, stream>>>(
                        P, nullptr, 0, M, VT + (long long)z * D * M, nullptr, 0, M,
                        out + ((long long)(b0 + z) * N + n0) * D, nullptr, 0, D, nullptr, M);
                }
            }
        }
    }
    (void)in_sizes; (void)n_in; (void)out_size;
}